// Round 4
// baseline (188.330 us; speedup 1.0000x reference)
//
#include <hip/hip_runtime.h>
#include <stdint.h>

// BitConv1d: out = conv1d(x, sign(w), pad=1) * mean|w| * scale
// (x_scale cancels exactly: conv(x/s,w)*s == conv(x,w))
//
// Structure (r4): block = 256co x 64l, FULL ci depth staged in LDS once
// (512ci x 66l bf16 = 67.6KB, 2 blocks/CU). ONE barrier per block; the
// K-loop is read-only streaming (A-frags from L2-resident w, B from LDS,
// no syncs) so blocks can't phase-lock and the compiler pipelines freely.
//
// Workspace: float[1024] @0 partial |w| sums; float @4096 final factor;
//            ushort[786432] @8192 sign(w) bf16, layout [t][ci>>3][co][ci&7]

#define CIN   512
#define COUT  512
#define LLEN  4096
#define NBAT  16
#define KW    3
#define WELEMS (COUT*CIN*KW)

typedef __bf16 bf16x8 __attribute__((ext_vector_type(8)));
typedef float  f32x4  __attribute__((ext_vector_type(4)));

__device__ __forceinline__ uint32_t f2bf(float f) {
    union { float f; uint32_t u; } v; v.f = f;
    return (v.u + 0x7fffu + ((v.u >> 16) & 1u)) >> 16;   // RNE
}

// ---- pack sign(w) -> bf16 (MFMA layout) + per-block |w| partial sums ----
__global__ __launch_bounds__(256) void pack_w(const float* __restrict__ w,
                                              unsigned short* __restrict__ wsw,
                                              float* __restrict__ partial) {
    __shared__ float red[256];
    int tid = threadIdx.x;
    int idx = blockIdx.x * 256 + tid;          // co*512 + ci
    float s = 0.f;
    int co = idx >> 9, ci = idx & 511;
#pragma unroll
    for (int t = 0; t < KW; ++t) {
        float v = w[idx * 3 + t];
        s += fabsf(v);
        unsigned short b = (v > 0.f) ? 0x3F80 : ((v < 0.f) ? 0xBF80 : 0);
        wsw[((t * 64 + (ci >> 3)) * 512 + co) * 8 + (ci & 7)] = b;
    }
    red[tid] = s;
    __syncthreads();
    for (int off = 128; off > 0; off >>= 1) {
        if (tid < off) red[tid] += red[tid + off];
        __syncthreads();
    }
    if (tid == 0) partial[blockIdx.x] = red[0];
}

__global__ __launch_bounds__(256) void wscale_final(const float* __restrict__ partial,
                                                    const float* __restrict__ scale,
                                                    float* __restrict__ fac) {
    __shared__ float red[256];
    int tid = threadIdx.x;
    red[tid] = partial[tid] + partial[tid + 256] + partial[tid + 512] + partial[tid + 768];
    __syncthreads();
    for (int off = 128; off > 0; off >>= 1) {
        if (tid < off) red[tid] += red[tid + off];
        __syncthreads();
    }
    if (tid == 0) fac[0] = red[0] * (1.0f / (float)WELEMS) * scale[0];
}

// LDS layout: row ll (0..65, = local l + 1; halos at 0/65), 1024B per row =
// 64 slots of 16B (slot = ci/8), swizzled: slot_phys = slot ^ (ll & 7).
// Write: lane's u32 covers (ci, ci+1) at byte slot*16 + (ci&7)*2 -> 2-way.
// Read: ds_read_b128 by (16 m-lanes x 4 ks) -> 32 groups x 2 lanes -> 2-way.
__global__ __launch_bounds__(256, 2) void conv_mfma(const float* __restrict__ x,
                                                    const unsigned short* __restrict__ wsw,
                                                    const float* __restrict__ fac,
                                                    float* __restrict__ out) {
    // XCD swizzle (2048 blocks % 8 == 0, bijective): co-pair blocks sharing
    // an x tile stay adjacent on one XCD.
    int swz = (blockIdx.x & 7) * 256 + (blockIdx.x >> 3);
    int cob = swz & 1;            // 2 co tiles of 256
    int lb  = (swz >> 1) & 63;    // 64 l tiles of 64
    int n   = swz >> 7;           // 16 samples
    int co0 = cob * 256;
    int l0  = lb * 64;

    __shared__ char Bs[66 * 1024];   // 67.6 KB

    int tid  = threadIdx.x;
    int wave = tid >> 6;
    int lane = tid & 63;
    int m    = lane & 15;
    int ks   = lane >> 4;

    // ================= stage x tile (once) =================
    {
        const float* r0 = x + ((size_t)(n * 512 + 2 * tid)) * LLEN + l0;  // ci=2*tid
        const float* r1 = r0 + LLEN;
        int sbase = ((tid >> 2) << 4) | ((tid & 3) << 2);   // slot(ci)=tid>>2, byte within
#pragma unroll 4
        for (int q = 0; q < 16; ++q) {
            float4 a = reinterpret_cast<const float4*>(r0)[q];
            float4 b = reinterpret_cast<const float4*>(r1)[q];
#pragma unroll
            for (int e = 0; e < 4; ++e) {
                int ll = q * 4 + e + 1;                      // 1..64
                uint32_t pk = f2bf(((const float*)&a)[e])
                            | (f2bf(((const float*)&b)[e]) << 16);
                int off = ll * 1024 + ((((tid >> 2) ^ (ll & 7)) << 4) | ((tid & 3) << 2));
                *reinterpret_cast<uint32_t*>(Bs + off) = pk;
            }
        }
        // halos: ll=0 (l0-1), ll=65 (l0+64)
        float lo0 = 0.f, lo1 = 0.f, hi0 = 0.f, hi1 = 0.f;
        if (l0 > 0)            { lo0 = r0[-1]; lo1 = r1[-1]; }
        if (l0 + 64 < LLEN)    { hi0 = r0[64]; hi1 = r1[64]; }
        *reinterpret_cast<uint32_t*>(Bs + sbase) = f2bf(lo0) | (f2bf(lo1) << 16);
        *reinterpret_cast<uint32_t*>(Bs + 65 * 1024
            + ((((tid >> 2) ^ 1) << 4) | ((tid & 3) << 2))) = f2bf(hi0) | (f2bf(hi1) << 16);
    }
    __syncthreads();     // the ONLY barrier; LDS is read-only below

    // ================= K loop: pure streaming =================
    const char* wb = (const char*)wsw;
    int aoff[4];
#pragma unroll
    for (int ms = 0; ms < 4; ++ms)
        aoff[ms] = ks * 8192 + (co0 + wave * 64 + ms * 16 + m) * 16;

    f32x4 acc[4][4];
#pragma unroll
    for (int i = 0; i < 4; ++i)
#pragma unroll
        for (int j = 0; j < 4; ++j) acc[i][j] = (f32x4){0.f, 0.f, 0.f, 0.f};

#pragma unroll 2
    for (int c = 0; c < 16; ++c) {
#pragma unroll
        for (int t = 0; t < KW; ++t) {
            bf16x8 afr[4], bfr[4];
#pragma unroll
            for (int ms = 0; ms < 4; ++ms)
                afr[ms] = *reinterpret_cast<const bf16x8*>(
                    wb + t * 524288 + c * 32768 + aoff[ms]);
#pragma unroll
            for (int ns = 0; ns < 4; ++ns) {
                int ll = ns * 16 + m + t;                    // 0..65
                bfr[ns] = *reinterpret_cast<const bf16x8*>(
                    Bs + ll * 1024 + (((c * 4 + ks) ^ (ll & 7)) << 4));
            }
#pragma unroll
            for (int ms = 0; ms < 4; ++ms)
#pragma unroll
                for (int ns = 0; ns < 4; ++ns)
                    acc[ms][ns] = __builtin_amdgcn_mfma_f32_16x16x32_bf16(
                        afr[ms], bfr[ns], acc[ms][ns], 0, 0, 0);
        }
    }

    // ================= epilogue =================
    float fscale = fac[0];
    int r4 = (lane >> 4) * 4;
#pragma unroll
    for (int ms = 0; ms < 4; ++ms) {
#pragma unroll
        for (int ns = 0; ns < 4; ++ns) {
            int col  = l0 + ns * 16 + m;
            int row0 = co0 + wave * 64 + ms * 16 + r4;
            float* o = out + ((size_t)(n * 512 + row0)) * LLEN + col;
#pragma unroll
            for (int r = 0; r < 4; ++r)
                o[(size_t)r * LLEN] = acc[ms][ns][r] * fscale;
        }
    }
}

extern "C" void kernel_launch(void* const* d_in, const int* in_sizes, int n_in,
                              void* d_out, int out_size, void* d_ws, size_t ws_size,
                              hipStream_t stream) {
    const float* x     = (const float*)d_in[0];
    const float* w     = (const float*)d_in[1];
    const float* scale = (const float*)d_in[2];
    float* out = (float*)d_out;

    float* partials = (float*)d_ws;                               // 1024 floats
    float* fac      = (float*)((char*)d_ws + 4096);               // 1 float
    unsigned short* wsw = (unsigned short*)((char*)d_ws + 8192);  // 786432 bf16

    pack_w<<<(COUT * CIN) / 256, 256, 0, stream>>>(w, wsw, partials);
    wscale_final<<<1, 256, 0, stream>>>(partials, scale, fac);
    conv_mfma<<<NBAT * 2 * 64, 256, 0, stream>>>(x, wsw, fac, out);
}

// Round 5
// 148.376 us; speedup vs baseline: 1.2693x; 1.2693x over previous
//
#include <hip/hip_runtime.h>
#include <stdint.h>

// BitConv1d: out = conv1d(x, sign(w), pad=1) * mean|w| * scale
// (x_scale cancels exactly: conv(x/s,w)*s == conv(x,w))
//
// r5 structure = r3 (141us) + A staged via global_load_lds double-buffer:
//   128co x 128l block, 4 waves 2x2, acc 4x4, ci chunks of 32.
//   A (sign w): DMA'd 24KB/chunk into LDS (async, no VGPR/VALU), dbuf.
//   B (x):      reg-staged fp32->bf16, dbuf LDS, issue-early/write-late.
//   One raw s_barrier per chunk; vmcnt only drained after the MFMA cluster.
//
// Workspace: float[1024] @0 partial |w| sums; float @4096 final factor;
//            ushort[786432] @8192 sign(w) bf16, layout [t][ci>>3][co][ci&7]

#define CIN   512
#define COUT  512
#define LLEN  4096
#define NBAT  16
#define KW    3
#define WELEMS (COUT*CIN*KW)

typedef __bf16 bf16x8 __attribute__((ext_vector_type(8)));
typedef float  f32x4  __attribute__((ext_vector_type(4)));

#define DMA16(g, l) __builtin_amdgcn_global_load_lds( \
    (const __attribute__((address_space(1))) uint32_t*)(g), \
    (__attribute__((address_space(3))) uint32_t*)(l), 16, 0, 0)

__device__ __forceinline__ uint32_t f2bf(float f) {
    union { float f; uint32_t u; } v; v.f = f;
    return (v.u + 0x7fffu + ((v.u >> 16) & 1u)) >> 16;   // RNE
}

// ---- pack sign(w) -> bf16 (MFMA layout) + per-block |w| partial sums ----
__global__ __launch_bounds__(256) void pack_w(const float* __restrict__ w,
                                              unsigned short* __restrict__ wsw,
                                              float* __restrict__ partial) {
    __shared__ float red[256];
    int tid = threadIdx.x;
    int idx = blockIdx.x * 256 + tid;          // co*512 + ci
    float s = 0.f;
    int co = idx >> 9, ci = idx & 511;
#pragma unroll
    for (int t = 0; t < KW; ++t) {
        float v = w[idx * 3 + t];
        s += fabsf(v);
        unsigned short b = (v > 0.f) ? 0x3F80 : ((v < 0.f) ? 0xBF80 : 0);
        wsw[((t * 64 + (ci >> 3)) * 512 + co) * 8 + (ci & 7)] = b;
    }
    red[tid] = s;
    __syncthreads();
    for (int off = 128; off > 0; off >>= 1) {
        if (tid < off) red[tid] += red[tid + off];
        __syncthreads();
    }
    if (tid == 0) partial[blockIdx.x] = red[0];
}

__global__ __launch_bounds__(256) void wscale_final(const float* __restrict__ partial,
                                                    const float* __restrict__ scale,
                                                    float* __restrict__ fac) {
    __shared__ float red[256];
    int tid = threadIdx.x;
    red[tid] = partial[tid] + partial[tid + 256] + partial[tid + 512] + partial[tid + 768];
    __syncthreads();
    for (int off = 128; off > 0; off >>= 1) {
        if (tid < off) red[tid] += red[tid + off];
        __syncthreads();
    }
    if (tid == 0) fac[0] = red[0] * (1.0f / (float)WELEMS) * scale[0];
}

__global__ __launch_bounds__(256, 2) void conv_mfma(const float* __restrict__ x,
                                                    const unsigned short* __restrict__ wsw,
                                                    const float* __restrict__ fac,
                                                    float* __restrict__ out) {
    // XCD-aware bijective swizzle (2048 % 8 == 0): co-blocks sharing an x tile
    // run adjacent on one XCD -> x fetched ~once from HBM.
    int swz = (blockIdx.x & 7) * 256 + (blockIdx.x >> 3);
    int cob = swz & 3;
    int lb  = (swz >> 2) & 31;
    int n   = swz >> 7;
    int co0 = cob * 128;
    int l0  = lb * 128;

    __shared__ char As[2][24576];   // [t3][ks4][co128] x 16B, linear (DMA dest)
    __shared__ char Bs[2][8320];    // [ll130][32ci] bf16, 64B rows, XOR swizzle

    int tid  = threadIdx.x;
    int wave = tid >> 6;
    int lane = tid & 63;
    int wco  = (wave >> 1) * 64;
    int wl   = (wave & 1) * 64;
    int m    = lane & 15;
    int ks   = lane >> 4;
    const int p  = tid & 15;      // ci pair (2p, 2p+1)
    const int fb = tid >> 4;      // float4 column

    const float* xbase = x + (size_t)(n * 512) * LLEN;
    const char*  wb    = (const char*)wsw;

    // ---- A: async DMA of one 24KB chunk tile, 6 x 16B per thread ----
    auto DMAA = [&](int c, char* Ad) {
#pragma unroll
        for (int it = 0; it < 6; ++it) {
            int g = it * 256 + tid;              // 16B unit 0..1535
            int s = g >> 7;                      // = t*4 + ks
            int r = g & 127;                     // co within tile
            const char* src = wb +
                ((((s >> 2) * 64 + c * 4 + (s & 3)) * 512) + (co0 + r)) * 16;
            DMA16(src, Ad + g * 16);
        }
    };

    // ---- B: reg load + convert + swizzled LDS write (r3-proven layout) ----
    float4 b0[2], b1[2];
    float  hReg = 0.f;
    auto LOADB = [&](int c) {
        const float* xrow0 = xbase + (size_t)(c * 32 + 2 * p) * LLEN + l0;
        const float* xrow1 = xrow0 + LLEN;
        b0[0] = reinterpret_cast<const float4*>(xrow0)[fb];
        b1[0] = reinterpret_cast<const float4*>(xrow1)[fb];
        b0[1] = reinterpret_cast<const float4*>(xrow0)[fb + 16];
        b1[1] = reinterpret_cast<const float4*>(xrow1)[fb + 16];
        if (tid < 32)
            hReg = (l0 > 0) ? xbase[(size_t)(c * 32 + tid) * LLEN + l0 - 1] : 0.f;
        else if (tid < 64)
            hReg = (l0 + 128 < LLEN) ? xbase[(size_t)(c * 32 + tid - 32) * LLEN + l0 + 128] : 0.f;
    };
    auto WRITEB = [&](char* BsD) {
        int kslot = p >> 2, jj = (2 * p) & 7;
#pragma unroll
        for (int half = 0; half < 2; ++half) {
#pragma unroll
            for (int e = 0; e < 4; ++e) {
                int ll = (fb + half * 16) * 4 + 1 + e;        // 1..128
                uint32_t pk = f2bf(((const float*)&b0[half])[e])
                            | (f2bf(((const float*)&b1[half])[e]) << 16);
                *reinterpret_cast<uint32_t*>(
                    BsD + ll * 64 + ((kslot ^ ((ll >> 1) & 3)) << 4) + jj * 2) = pk;
            }
        }
        if (tid < 32) {
            *reinterpret_cast<unsigned short*>(
                BsD + ((tid >> 3) << 4) + (tid & 7) * 2) = (unsigned short)f2bf(hReg);
        } else if (tid < 64) {
            int ci = tid - 32, ll = 129;
            *reinterpret_cast<unsigned short*>(
                BsD + ll * 64 + (((ci >> 3) ^ ((ll >> 1) & 3)) << 4) + (ci & 7) * 2)
                = (unsigned short)f2bf(hReg);
        }
    };

    f32x4 acc[4][4];
#pragma unroll
    for (int i = 0; i < 4; ++i)
#pragma unroll
        for (int j = 0; j < 4; ++j) acc[i][j] = (f32x4){0.f, 0.f, 0.f, 0.f};

    // prologue: stage chunk 0 (A via DMA, B via regs)
    DMAA(0, As[0]);
    LOADB(0);
    WRITEB(Bs[0]);                               // implicit vmcnt waits on b regs
    asm volatile("s_waitcnt vmcnt(0)" ::: "memory");   // A DMA done
    __syncthreads();

    for (int c = 0; c < 16; ++c) {
        if (c < 15) {
            DMAA(c + 1, As[(c + 1) & 1]);        // async into other buffer
            LOADB(c + 1);                        // regs, in flight across compute
        }
        __builtin_amdgcn_sched_barrier(0);       // issue block stays above compute

        const char* Ac = As[c & 1];
        const char* Bc = Bs[c & 1];
#pragma unroll
        for (int t = 0; t < KW; ++t) {
            bf16x8 afr[4], bfr[4];
#pragma unroll
            for (int ms = 0; ms < 4; ++ms)
                afr[ms] = *reinterpret_cast<const bf16x8*>(
                    Ac + ((t * 4 + ks) * 128 + wco + ms * 16 + m) * 16);
#pragma unroll
            for (int ns = 0; ns < 4; ++ns) {
                int ll = wl + ns * 16 + m + t;
                bfr[ns] = *reinterpret_cast<const bf16x8*>(
                    Bc + ll * 64 + ((ks ^ ((ll >> 1) & 3)) << 4));
            }
#pragma unroll
            for (int ms = 0; ms < 4; ++ms)
#pragma unroll
                for (int ns = 0; ns < 4; ++ns)
                    acc[ms][ns] = __builtin_amdgcn_mfma_f32_16x16x32_bf16(
                        afr[ms], bfr[ns], acc[ms][ns], 0, 0, 0);
        }

        if (c < 15) {
            asm volatile("s_waitcnt vmcnt(0)" ::: "memory");   // B regs + A DMA landed
            WRITEB(Bs[(c + 1) & 1]);
            asm volatile("s_waitcnt lgkmcnt(0)" ::: "memory"); // my LDS writes committed
            __builtin_amdgcn_s_barrier();                      // publish chunk c+1
            __builtin_amdgcn_sched_barrier(0);
        }
    }

    // ---- epilogue: D lane map col=lane&15, row=(lane>>4)*4+r ----
    float fscale = fac[0];
    int r4 = (lane >> 4) * 4;
#pragma unroll
    for (int ms = 0; ms < 4; ++ms) {
#pragma unroll
        for (int ns = 0; ns < 4; ++ns) {
            int col  = l0 + wl + ns * 16 + m;
            int row0 = co0 + wco + ms * 16 + r4;
            float* o = out + ((size_t)(n * 512 + row0)) * LLEN + col;
#pragma unroll
            for (int r = 0; r < 4; ++r)
                o[(size_t)r * LLEN] = acc[ms][ns][r] * fscale;
        }
    }
}

extern "C" void kernel_launch(void* const* d_in, const int* in_sizes, int n_in,
                              void* d_out, int out_size, void* d_ws, size_t ws_size,
                              hipStream_t stream) {
    const float* x     = (const float*)d_in[0];
    const float* w     = (const float*)d_in[1];
    const float* scale = (const float*)d_in[2];
    float* out = (float*)d_out;

    float* partials = (float*)d_ws;                               // 1024 floats
    float* fac      = (float*)((char*)d_ws + 4096);               // 1 float
    unsigned short* wsw = (unsigned short*)((char*)d_ws + 8192);  // 786432 bf16

    pack_w<<<(COUT * CIN) / 256, 256, 0, stream>>>(w, wsw, partials);
    wscale_final<<<1, 256, 0, stream>>>(partials, scale, fac);
    conv_mfma<<<NBAT * 4 * 32, 256, 0, stream>>>(x, wsw, fac, out);
}